// Round 6
// baseline (1841.043 us; speedup 1.0000x reference)
//
#include <hip/hip_runtime.h>

#define NN 8192
#define NE 65536

typedef __attribute__((ext_vector_type(8))) __bf16 bf16x8;
typedef __attribute__((ext_vector_type(4))) float f32x4;

typedef __attribute__((address_space(1))) const void* as1_cvoid;
typedef __attribute__((address_space(3))) void* as3_void;

__device__ __forceinline__ float bf2f(unsigned short s) {
  union { unsigned u; float f; } z; z.u = ((unsigned)s) << 16; return z.f;
}
__device__ __forceinline__ unsigned short f2bf(float f) {
  union { float f; unsigned u; } z; z.f = f;
  return (unsigned short)((z.u + 0x7FFFu + ((z.u >> 16) & 1u)) >> 16);
}
__device__ __forceinline__ void gl_lds16(const void* g, void* l) {
  __builtin_amdgcn_global_load_lds((as1_cvoid)g, (as3_void)l, 16, 0, 0);
}

// device-scope grid barrier: all blocks co-resident (1 block/CU, grid<=256).
// release part of fetch_add emits L2 writeback; acquire load emits invalidate
// -> cross-XCD visibility for e/v written before the barrier.
__device__ __forceinline__ void gbar(int* bar, int target) {
  __syncthreads();
  if (threadIdx.x == 0) {
    __hip_atomic_fetch_add(bar, 1, __ATOMIC_ACQ_REL, __HIP_MEMORY_SCOPE_AGENT);
    while (__hip_atomic_load(bar, __ATOMIC_ACQUIRE, __HIP_MEMORY_SCOPE_AGENT) < target)
      __builtin_amdgcn_s_sleep(2);
  }
  __syncthreads();
}

__global__ __launch_bounds__(256) void k_zero_i32(int* p, int n) {
  int t = blockIdx.x * 256 + threadIdx.x;
  if (t < n) p[t] = 0;
}

// pack W (K x 128 row-major fp32) -> bf16 slabs of 4096 elems, slab layout
// [l4][n][8]: element (n, k=s*32+l4*8+j) at t = s*4096 + l4*1024 + n*8 + j.
__device__ __forceinline__ void packone(int t, const float* src, unsigned short* dst, int K) {
  int s = t >> 12;
  int rem = t & 4095;
  int l4 = rem >> 10;
  int rem2 = rem & 1023;
  int n = rem2 >> 3, j = rem2 & 7;
  int k = s * 32 + l4 * 8 + j;
  dst[t] = (k < K) ? f2bf(src[k * 128 + n]) : (unsigned short)0;
}

__global__ __launch_bounds__(256) void k_pack_all(
    const float* ve1, unsigned short* tve1, const float* ve2, unsigned short* tve2,
    const float* ee1, unsigned short* tee1, const float* ee2, unsigned short* tee2,
    const float* em1, unsigned short* tem1, const float* em2, unsigned short* tem2,
    const float* nm1, unsigned short* tnm1, const float* nm2, unsigned short* tnm2,
    const float* dc1, unsigned short* tdc1) {
  int t = blockIdx.x * 256 + threadIdx.x;
  if (t < 4096) packone(t, ve1, tve1, 8);
  else if (t < 20480) packone(t - 4096, ve2, tve2, 128);
  else if (t < 24576) packone(t - 20480, ee1, tee1, 6);
  else if (t < 40960) packone(t - 24576, ee2, tee2, 128);
  else if (t < 90112) packone(t - 40960, em1, tem1, 384);
  else if (t < 106496) packone(t - 90112, em2, tem2, 128);
  else if (t < 139264) packone(t - 106496, nm1, tnm1, 256);
  else if (t < 155648) packone(t - 139264, nm2, tnm2, 128);
  else if (t < 172032) packone(t - 155648, dc1, tdc1, 128);
}

__global__ __launch_bounds__(256) void k_prep_nodes(const int* __restrict__ sn,
                                                    const float* __restrict__ vf,
                                                    unsigned short* __restrict__ X) {
  int n = blockIdx.x * 256 + threadIdx.x;
  if (n >= NN) return;
  unsigned short* row = &X[(size_t)n * 32];
  int s = sn[n];
  row[0] = f2bf(s == 0 ? 1.f : 0.f);
  row[1] = f2bf(s == 1 ? 1.f : 0.f);
#pragma unroll
  for (int j = 0; j < 6; j++) row[2 + j] = f2bf(vf[n * 6 + j]);
#pragma unroll
  for (int j = 8; j < 32; j++) row[j] = 0;
}

__global__ __launch_bounds__(256) void k_prep_edges(const int* __restrict__ eidx,
                                                    const float* __restrict__ wc,
                                                    const float* __restrict__ mc,
                                                    unsigned short* __restrict__ X,
                                                    int* __restrict__ cnt) {
  int t = blockIdx.x * 256 + threadIdx.x;
  if (t >= NE) return;
  int r = eidx[t], c = eidx[NE + t];
  float ex = wc[c * 2] - wc[r * 2];
  float ey = wc[c * 2 + 1] - wc[r * 2 + 1];
  float mx = mc[c * 2] - mc[r * 2];
  float my = mc[c * 2 + 1] - mc[r * 2 + 1];
  unsigned short* row = &X[(size_t)t * 32];
  row[0] = f2bf(ex); row[1] = f2bf(ey); row[2] = f2bf(sqrtf(ex * ex + ey * ey));
  row[3] = f2bf(mx); row[4] = f2bf(my); row[5] = f2bf(sqrtf(mx * mx + my * my));
#pragma unroll
  for (int j = 6; j < 32; j++) row[j] = 0;
  atomicAdd(&cnt[r], 1);
}

__global__ __launch_bounds__(1024) void k_scan(const int* __restrict__ cnt,
                                               int* __restrict__ offs,
                                               int* __restrict__ cursor) {
  __shared__ int sd[1024];
  int tid = threadIdx.x;
  int loc[8];
  int s = 0;
#pragma unroll
  for (int i = 0; i < 8; i++) { loc[i] = s; s += cnt[tid * 8 + i]; }
  sd[tid] = s;
  __syncthreads();
  for (int o = 1; o < 1024; o <<= 1) {
    int vv = 0;
    if (tid >= o) vv = sd[tid - o];
    __syncthreads();
    sd[tid] += vv;
    __syncthreads();
  }
  int base = (tid == 0) ? 0 : sd[tid - 1];
#pragma unroll
  for (int i = 0; i < 8; i++) {
    int o = base + loc[i];
    offs[tid * 8 + i] = o;
    cursor[tid * 8 + i] = o;
  }
  if (tid == 1023) offs[8192] = sd[1023];
}

__global__ __launch_bounds__(256) void k_fill(const int* __restrict__ eidx,
                                              int* __restrict__ cursor,
                                              int* __restrict__ elist) {
  int t = blockIdx.x * 256 + threadIdx.x;
  if (t >= NE) return;
  int r = eidx[t];
  int pos = atomicAdd(&cursor[r], 1);
  elist[pos] = t;
}

// ================= persistent kernel: all 15 message-passing steps ==========
// 256 blocks x 512 threads, 1 block/CU (LDS 160KB). Edge weights resident in
// LDS for the whole kernel. Per step: EDGE (8 waves x 32 rows) -> grid barrier
// -> AGG (own 32 nodes -> LDS) -> syncthreads -> NODE (waves 0-1, B from L2)
// -> grid barrier.
__global__ __launch_bounds__(512, 1) void k_steps(
    unsigned short* __restrict__ vbuf, unsigned short* __restrict__ ebuf,
    const int* __restrict__ eidx,
    const int* __restrict__ offs, const int* __restrict__ elist,
    const unsigned short* __restrict__ W1e, const float* __restrict__ b1e,
    const unsigned short* __restrict__ W2e, const float* __restrict__ b2e,
    const float* __restrict__ lge, const float* __restrict__ lbe,
    const unsigned short* __restrict__ W1n, const float* __restrict__ b1n,
    const unsigned short* __restrict__ W2n, const float* __restrict__ b2n,
    const float* __restrict__ lgn, const float* __restrict__ lbn,
    int* __restrict__ bar) {
  __shared__ __align__(16) unsigned short Wres[65536];  // 128 KB edge weights
  __shared__ __align__(16) unsigned short H1c[16384];   // 32 KB scratch
  const int tid = threadIdx.x;
  const int lane = tid & 63, wid = tid >> 6;
  const int l4 = lane >> 4, l15 = lane & 15;
  const int blk = blockIdx.x;
  const int row0 = blk * 256;
  const int hb = wid * 2048;
  const int grid = (int)gridDim.x;

  // ---- stage edge weights ONCE ----
#pragma unroll
  for (int u = 0; u < 12; ++u)
    gl_lds16(W1e + (u * 512 + tid) * 8, &Wres[(u * 512 + tid) * 8]);
#pragma unroll
  for (int u = 0; u < 4; ++u)
    gl_lds16(W2e + (u * 512 + tid) * 8, &Wres[49152 + (u * 512 + tid) * 8]);

  int rg[2], ridx[2], cidx[2];
#pragma unroll
  for (int g = 0; g < 2; g++) {
    rg[g] = row0 + wid * 32 + g * 16 + l15;
    ridx[g] = eidx[rg[g]];
    cidx[g] = eidx[NE + rg[g]];
  }
  const int nrow = blk * 32 + wid * 16 + l15;  // node-phase row (wid<2)

  int epoch = 0;
  for (int step = 0; step < 15; ++step) {
    // =================== EDGE ===================
    {
      bf16x8 af[2][12];
#pragma unroll
      for (int g = 0; g < 2; g++) {
#pragma unroll
        for (int s = 0; s < 4; s++)
          af[g][s] = *(const bf16x8*)&vbuf[(size_t)ridx[g] * 128 + s * 32 + l4 * 8];
#pragma unroll
        for (int s = 0; s < 4; s++)
          af[g][4 + s] = *(const bf16x8*)&vbuf[(size_t)cidx[g] * 128 + s * 32 + l4 * 8];
#pragma unroll
        for (int s = 0; s < 4; s++)
          af[g][8 + s] = *(const bf16x8*)&ebuf[(size_t)rg[g] * 128 + s * 32 + l4 * 8];
      }
      __syncthreads();  // step0: weight staging drained; also H1c reuse fence

      f32x4 acc1[2][8] = {};
#pragma unroll
      for (int s = 0; s < 12; ++s)
#pragma unroll
        for (int ct = 0; ct < 8; ct++) {
          bf16x8 b = *(const bf16x8*)&Wres[s * 4096 + l4 * 1024 + (ct * 16 + l15) * 8];
          acc1[0][ct] = __builtin_amdgcn_mfma_f32_16x16x32_bf16(af[0][s], b, acc1[0][ct], 0, 0, 0);
          acc1[1][ct] = __builtin_amdgcn_mfma_f32_16x16x32_bf16(af[1][s], b, acc1[1][ct], 0, 0, 0);
        }

      bf16x8 hf[2][4];
#pragma unroll
      for (int g = 0; g < 2; g++) {
#pragma unroll
        for (int ct = 0; ct < 8; ct++) {
          float bb = b1e[ct * 16 + l15];
          int ch = ct * 2 + (l15 >> 3);
#pragma unroll
          for (int r = 0; r < 4; r++) {
            float h = fmaxf(acc1[g][ct][r] + bb, 0.f);
            H1c[hb + (ch * 16 + l4 * 4 + r) * 8 + (l15 & 7)] = f2bf(h);
          }
        }
#pragma unroll
        for (int kt = 0; kt < 4; kt++)
          hf[g][kt] = *(const bf16x8*)&H1c[hb + ((kt * 4 + l4) * 16 + l15) * 8];
      }

      f32x4 acc2[2][8] = {};
#pragma unroll
      for (int s = 0; s < 4; ++s)
#pragma unroll
        for (int ct = 0; ct < 8; ct++) {
          bf16x8 b = *(const bf16x8*)&Wres[49152 + s * 4096 + l4 * 1024 + (ct * 16 + l15) * 8];
          acc2[0][ct] = __builtin_amdgcn_mfma_f32_16x16x32_bf16(hf[0][s], b, acc2[0][ct], 0, 0, 0);
          acc2[1][ct] = __builtin_amdgcn_mfma_f32_16x16x32_bf16(hf[1][s], b, acc2[1][ct], 0, 0, 0);
        }

#pragma unroll
      for (int g = 0; g < 2; g++) {
        float s0[4] = {0, 0, 0, 0}, s1v[4] = {0, 0, 0, 0};
#pragma unroll
        for (int ct = 0; ct < 8; ct++) {
          float bb = b2e[ct * 16 + l15];
#pragma unroll
          for (int r = 0; r < 4; r++) {
            int rr = row0 + wid * 32 + g * 16 + l4 * 4 + r;
            float x = acc2[g][ct][r] + bb + bf2f(ebuf[(size_t)rr * 128 + ct * 16 + l15]);
            acc2[g][ct][r] = x;
            s0[r] += x;
            s1v[r] += x * x;
          }
        }
#pragma unroll
        for (int m = 1; m < 16; m <<= 1)
#pragma unroll
          for (int r = 0; r < 4; r++) {
            s0[r] += __shfl_xor(s0[r], m, 64);
            s1v[r] += __shfl_xor(s1v[r], m, 64);
          }
#pragma unroll
        for (int ct = 0; ct < 8; ct++) {
          float gsc = lge[ct * 16 + l15], bsc = lbe[ct * 16 + l15];
          int ch = ct * 2 + (l15 >> 3);
#pragma unroll
          for (int r = 0; r < 4; r++) {
            float mean = s0[r] * (1.f / 128.f);
            float var = s1v[r] * (1.f / 128.f) - mean * mean;
            float y = (acc2[g][ct][r] - mean) * rsqrtf(var + 1e-5f) * gsc + bsc;
            H1c[hb + (ch * 16 + l4 * 4 + r) * 8 + (l15 & 7)] = f2bf(y);
          }
        }
#pragma unroll
        for (int i = 0; i < 4; i++) {
          *(uint4*)&ebuf[(size_t)(row0 + wid * 32 + g * 16 + l15) * 128 + (i * 4 + l4) * 8] =
              *(const uint4*)&H1c[hb + ((i * 4 + l4) * 16 + l15) * 8];
        }
      }
    }
    gbar(bar, ++epoch * grid);  // e visible to all XCDs

    // =================== AGG (own 32 nodes -> H1c[0..8KB)) ===================
    {
      int c = tid & 15;
      int n = blk * 32 + (tid >> 4);
      int beg = offs[n], end = offs[n + 1];
      float a0[8] = {0, 0, 0, 0, 0, 0, 0, 0}, a1[8] = {0, 0, 0, 0, 0, 0, 0, 0};
      int q = beg;
      for (; q + 2 <= end; q += 2) {
        uint4 u0 = *(const uint4*)&ebuf[(size_t)elist[q] * 128 + c * 8];
        uint4 u1 = *(const uint4*)&ebuf[(size_t)elist[q + 1] * 128 + c * 8];
        const unsigned short* p0 = (const unsigned short*)&u0;
        const unsigned short* p1 = (const unsigned short*)&u1;
#pragma unroll
        for (int j = 0; j < 8; j++) { a0[j] += bf2f(p0[j]); a1[j] += bf2f(p1[j]); }
      }
      if (q < end) {
        uint4 u0 = *(const uint4*)&ebuf[(size_t)elist[q] * 128 + c * 8];
        const unsigned short* p0 = (const unsigned short*)&u0;
#pragma unroll
        for (int j = 0; j < 8; j++) a0[j] += bf2f(p0[j]);
      }
      union { uint4 u; unsigned short s[8]; } t;
#pragma unroll
      for (int j = 0; j < 8; j++) t.s[j] = f2bf(a0[j] + a1[j]);
      *(uint4*)&H1c[(tid >> 4) * 128 + c * 8] = t.u;
    }
    __syncthreads();

    // =================== NODE (waves 0-1; B-frags from L2) ===================
    if (wid < 2) {
      bf16x8 av[8];
#pragma unroll
      for (int s = 0; s < 4; s++)
        av[s] = *(const bf16x8*)&vbuf[(size_t)nrow * 128 + s * 32 + l4 * 8];
#pragma unroll
      for (int s = 0; s < 4; s++)
        av[4 + s] = *(const bf16x8*)&H1c[(wid * 16 + l15) * 128 + s * 32 + l4 * 8];
      f32x4 acc1[8] = {};
#pragma unroll
      for (int sl = 0; sl < 8; ++sl)
#pragma unroll
        for (int ct = 0; ct < 8; ct++) {
          bf16x8 b = *(const bf16x8*)&W1n[sl * 4096 + l4 * 1024 + (ct * 16 + l15) * 8];
          acc1[ct] = __builtin_amdgcn_mfma_f32_16x16x32_bf16(av[sl], b, acc1[ct], 0, 0, 0);
        }
      const int thb = 4096 + wid * 2048;
      bf16x8 hf[4];
#pragma unroll
      for (int ct = 0; ct < 8; ct++) {
        float bb = b1n[ct * 16 + l15];
        int ch = ct * 2 + (l15 >> 3);
#pragma unroll
        for (int r = 0; r < 4; r++) {
          float h = fmaxf(acc1[ct][r] + bb, 0.f);
          H1c[thb + (ch * 16 + l4 * 4 + r) * 8 + (l15 & 7)] = f2bf(h);
        }
      }
#pragma unroll
      for (int kt = 0; kt < 4; kt++)
        hf[kt] = *(const bf16x8*)&H1c[thb + ((kt * 4 + l4) * 16 + l15) * 8];
      f32x4 acc2[8] = {};
#pragma unroll
      for (int sl = 0; sl < 4; ++sl)
#pragma unroll
        for (int ct = 0; ct < 8; ct++) {
          bf16x8 b = *(const bf16x8*)&W2n[sl * 4096 + l4 * 1024 + (ct * 16 + l15) * 8];
          acc2[ct] = __builtin_amdgcn_mfma_f32_16x16x32_bf16(hf[sl], b, acc2[ct], 0, 0, 0);
        }
      float s0[4] = {0, 0, 0, 0}, s1v[4] = {0, 0, 0, 0};
#pragma unroll
      for (int ct = 0; ct < 8; ct++) {
        float bb = b2n[ct * 16 + l15];
#pragma unroll
        for (int r = 0; r < 4; r++) {
          int rr = blk * 32 + wid * 16 + l4 * 4 + r;
          float x = acc2[ct][r] + bb + bf2f(vbuf[(size_t)rr * 128 + ct * 16 + l15]);
          acc2[ct][r] = x;
          s0[r] += x;
          s1v[r] += x * x;
        }
      }
#pragma unroll
      for (int m = 1; m < 16; m <<= 1)
#pragma unroll
        for (int r = 0; r < 4; r++) {
          s0[r] += __shfl_xor(s0[r], m, 64);
          s1v[r] += __shfl_xor(s1v[r], m, 64);
        }
#pragma unroll
      for (int ct = 0; ct < 8; ct++) {
        float gsc = lgn[ct * 16 + l15], bsc = lbn[ct * 16 + l15];
        int ch = ct * 2 + (l15 >> 3);
#pragma unroll
        for (int r = 0; r < 4; r++) {
          float mean = s0[r] * (1.f / 128.f);
          float var = s1v[r] * (1.f / 128.f) - mean * mean;
          float y = (acc2[ct][r] - mean) * rsqrtf(var + 1e-5f) * gsc + bsc;
          H1c[thb + (ch * 16 + l4 * 4 + r) * 8 + (l15 & 7)] = f2bf(y);
        }
      }
#pragma unroll
      for (int i = 0; i < 4; i++) {
        *(uint4*)&vbuf[(size_t)nrow * 128 + (i * 4 + l4) * 8] =
            *(const uint4*)&H1c[thb + ((i * 4 + l4) * 16 + l15) * 8];
      }
    }
    gbar(bar, ++epoch * grid);  // v visible to all XCDs
  }
}

// ------------------ encoder MLP (K=32 padded input, no residual) -------------
__global__ __launch_bounds__(256) void k_enc(const unsigned short* __restrict__ Xbuf,
                                             const unsigned short* __restrict__ W1T,
                                             const float* __restrict__ b1,
                                             const unsigned short* __restrict__ W2T,
                                             const float* __restrict__ b2,
                                             const float* __restrict__ lng,
                                             const float* __restrict__ lnb,
                                             unsigned short* __restrict__ outbuf) {
  __shared__ __align__(16) unsigned short Xt[64 * 40];
  __shared__ __align__(16) unsigned short H1[64 * 136];
  const int tid = threadIdx.x;
  const int row0 = blockIdx.x * 64;
  {
    int r = tid >> 2, c = tid & 3;
    *(uint4*)&Xt[r * 40 + c * 8] = *(const uint4*)&Xbuf[(size_t)(row0 + r) * 32 + c * 8];
  }
  __syncthreads();
  const int lane = tid & 63, wid = tid >> 6;
  const int l4 = lane >> 4, l15 = lane & 15;

  f32x4 acc1[8] = {};
  bf16x8 a = *(const bf16x8*)&Xt[(wid * 16 + l15) * 40 + l4 * 8];
#pragma unroll
  for (int ct = 0; ct < 8; ct++) {
    bf16x8 b = *(const bf16x8*)&W1T[l4 * 1024 + (ct * 16 + l15) * 8];
    acc1[ct] = __builtin_amdgcn_mfma_f32_16x16x32_bf16(a, b, acc1[ct], 0, 0, 0);
  }
#pragma unroll
  for (int ct = 0; ct < 8; ct++) {
    float bb = b1[ct * 16 + l15];
#pragma unroll
    for (int r = 0; r < 4; r++) {
      float h = fmaxf(acc1[ct][r] + bb, 0.f);
      H1[(wid * 16 + l4 * 4 + r) * 136 + ct * 16 + l15] = f2bf(h);
    }
  }
  bf16x8 hf[4];
#pragma unroll
  for (int kt = 0; kt < 4; kt++)
    hf[kt] = *(const bf16x8*)&H1[(wid * 16 + l15) * 136 + kt * 32 + l4 * 8];
  f32x4 acc2[8] = {};
#pragma unroll
  for (int kt = 0; kt < 4; kt++) {
#pragma unroll
    for (int ct = 0; ct < 8; ct++) {
      bf16x8 b = *(const bf16x8*)&W2T[kt * 4096 + l4 * 1024 + (ct * 16 + l15) * 8];
      acc2[ct] = __builtin_amdgcn_mfma_f32_16x16x32_bf16(hf[kt], b, acc2[ct], 0, 0, 0);
    }
  }
  float vals[8][4];
  float s0[4] = {0, 0, 0, 0}, s1[4] = {0, 0, 0, 0};
#pragma unroll
  for (int ct = 0; ct < 8; ct++) {
    float bb = b2[ct * 16 + l15];
#pragma unroll
    for (int r = 0; r < 4; r++) {
      float x = acc2[ct][r] + bb;
      vals[ct][r] = x;
      s0[r] += x;
      s1[r] += x * x;
    }
  }
#pragma unroll
  for (int m = 1; m < 16; m <<= 1) {
#pragma unroll
    for (int r = 0; r < 4; r++) {
      s0[r] += __shfl_xor(s0[r], m, 64);
      s1[r] += __shfl_xor(s1[r], m, 64);
    }
  }
#pragma unroll
  for (int ct = 0; ct < 8; ct++) {
    int colc = ct * 16 + l15;
    float g = lng[colc], bb = lnb[colc];
#pragma unroll
    for (int r = 0; r < 4; r++) {
      float mean = s0[r] * (1.f / 128.f);
      float var = s1[r] * (1.f / 128.f) - mean * mean;
      float y = (vals[ct][r] - mean) * rsqrtf(var + 1e-5f) * g + bb;
      H1[(wid * 16 + l4 * 4 + r) * 136 + colc] = f2bf(y);
    }
  }
#pragma unroll
  for (int i = 0; i < 4; i++) {
    int j = lane + i * 64;
    int r = j >> 4, ch = j & 15;
    *(uint4*)&outbuf[(size_t)(row0 + wid * 16 + r) * 128 + ch * 8] =
        *(const uint4*)&H1[(wid * 16 + r) * 136 + ch * 8];
  }
}

__global__ __launch_bounds__(256) void k_decode(const unsigned short* __restrict__ vbuf,
                                                const unsigned short* __restrict__ W1T,
                                                const float* __restrict__ b1,
                                                const float* __restrict__ w2,
                                                const float* __restrict__ b2,
                                                float* __restrict__ out) {
  __shared__ __align__(16) unsigned short Xt[64 * 136];
  __shared__ __align__(16) unsigned short H1[64 * 136];
  const int tid = threadIdx.x;
  const int row0 = blockIdx.x * 64;
  for (int i = tid; i < 64 * 16; i += 256) {
    int r = i >> 4, c = i & 15;
    *(uint4*)&Xt[r * 136 + c * 8] = *(const uint4*)&vbuf[(size_t)(row0 + r) * 128 + c * 8];
  }
  __syncthreads();
  const int lane = tid & 63, wid = tid >> 6;
  const int l4 = lane >> 4, l15 = lane & 15;
  f32x4 acc1[8] = {};
#pragma unroll
  for (int kt = 0; kt < 4; kt++) {
    bf16x8 a = *(const bf16x8*)&Xt[(wid * 16 + l15) * 136 + kt * 32 + l4 * 8];
#pragma unroll
    for (int ct = 0; ct < 8; ct++) {
      bf16x8 b = *(const bf16x8*)&W1T[kt * 4096 + l4 * 1024 + (ct * 16 + l15) * 8];
      acc1[ct] = __builtin_amdgcn_mfma_f32_16x16x32_bf16(a, b, acc1[ct], 0, 0, 0);
    }
  }
#pragma unroll
  for (int ct = 0; ct < 8; ct++) {
    float bb = b1[ct * 16 + l15];
#pragma unroll
    for (int r = 0; r < 4; r++) {
      float h = fmaxf(acc1[ct][r] + bb, 0.f);
      H1[(wid * 16 + l4 * 4 + r) * 136 + ct * 16 + l15] = f2bf(h);
    }
  }
  __syncthreads();
  for (int i = tid; i < 64 * 6; i += 256) {
    int r = i / 6, o = i % 6;
    float s = b2[o];
    for (int k = 0; k < 128; k++) s += bf2f(H1[r * 136 + k]) * w2[k * 6 + o];
    out[(size_t)(row0 + r) * 6 + o] = s;
  }
}

extern "C" void kernel_launch(void* const* d_in, const int* in_sizes, int n_in,
                              void* d_out, int out_size, void* d_ws, size_t ws_size,
                              hipStream_t stream) {
  (void)in_sizes; (void)n_in; (void)out_size; (void)ws_size;
  const float* wc = (const float*)d_in[0];
  const float* vf = (const float*)d_in[1];
  const float* mc = (const float*)d_in[2];
  const float* ve_w1 = (const float*)d_in[3];
  const float* ve_b1 = (const float*)d_in[4];
  const float* ve_w2 = (const float*)d_in[5];
  const float* ve_b2 = (const float*)d_in[6];
  const float* ee_w1 = (const float*)d_in[7];
  const float* ee_b1 = (const float*)d_in[8];
  const float* ee_w2 = (const float*)d_in[9];
  const float* ee_b2 = (const float*)d_in[10];
  const float* enc_g = (const float*)d_in[11];
  const float* enc_b = (const float*)d_in[12];
  const float* em_w1 = (const float*)d_in[13];
  const float* em_b1 = (const float*)d_in[14];
  const float* em_w2 = (const float*)d_in[15];
  const float* em_b2 = (const float*)d_in[16];
  const float* em_g = (const float*)d_in[17];
  const float* em_lb = (const float*)d_in[18];
  const float* nm_w1 = (const float*)d_in[19];
  const float* nm_b1 = (const float*)d_in[20];
  const float* nm_w2 = (const float*)d_in[21];
  const float* nm_b2 = (const float*)d_in[22];
  const float* nm_g = (const float*)d_in[23];
  const float* nm_lb = (const float*)d_in[24];
  const float* dec_w1 = (const float*)d_in[25];
  const float* dec_b1 = (const float*)d_in[26];
  const float* dec_w2 = (const float*)d_in[27];
  const float* dec_b2 = (const float*)d_in[28];
  const int* eidx = (const int*)d_in[29];
  const int* sn = (const int*)d_in[30];
  float* dout = (float*)d_out;

  char* w = (char*)d_ws;
  size_t off = 0;
  auto alloc = [&](size_t bytes) {
    char* p = w + off;
    off += (bytes + 255) & ~(size_t)255;
    return p;
  };
  unsigned short* v = (unsigned short*)alloc((size_t)NN * 128 * 2);
  unsigned short* e = (unsigned short*)alloc((size_t)NE * 128 * 2);
  unsigned short* Xve = (unsigned short*)alloc((size_t)NN * 32 * 2);
  unsigned short* Xee = (unsigned short*)alloc((size_t)NE * 32 * 2);
  unsigned short* tve1 = (unsigned short*)alloc(128 * 32 * 2);
  unsigned short* tve2 = (unsigned short*)alloc(128 * 128 * 2);
  unsigned short* tee1 = (unsigned short*)alloc(128 * 32 * 2);
  unsigned short* tee2 = (unsigned short*)alloc(128 * 128 * 2);
  unsigned short* tem1 = (unsigned short*)alloc(128 * 384 * 2);
  unsigned short* tem2 = (unsigned short*)alloc(128 * 128 * 2);
  unsigned short* tnm1 = (unsigned short*)alloc(128 * 256 * 2);
  unsigned short* tnm2 = (unsigned short*)alloc(128 * 128 * 2);
  unsigned short* tdc1 = (unsigned short*)alloc(128 * 128 * 2);
  int* cnt = (int*)alloc(NN * 4);
  int* bar = (int*)alloc(256);           // contiguous after cnt; zeroed together
  int* offsb = (int*)alloc((NN + 1) * 4);
  int* cursor = (int*)alloc(NN * 4);
  int* elist = (int*)alloc((size_t)NE * 4);

  k_zero_i32<<<33, 256, 0, stream>>>(cnt, NN + 64);  // cnt + bar
  k_pack_all<<<672, 256, 0, stream>>>(ve_w1, tve1, ve_w2, tve2, ee_w1, tee1, ee_w2, tee2,
                                      em_w1, tem1, em_w2, tem2, nm_w1, tnm1, nm_w2, tnm2,
                                      dec_w1, tdc1);
  k_prep_nodes<<<32, 256, 0, stream>>>(sn, vf, Xve);
  k_prep_edges<<<256, 256, 0, stream>>>(eidx, wc, mc, Xee, cnt);
  k_scan<<<1, 1024, 0, stream>>>(cnt, offsb, cursor);
  k_fill<<<256, 256, 0, stream>>>(eidx, cursor, elist);

  k_enc<<<128, 256, 0, stream>>>(Xve, tve1, ve_b1, tve2, ve_b2, enc_g, enc_b, v);
  k_enc<<<1024, 256, 0, stream>>>(Xee, tee1, ee_b1, tee2, ee_b2, enc_g, enc_b, e);

  k_steps<<<256, 512, 0, stream>>>(v, e, eidx, offsb, elist,
                                   tem1, em_b1, tem2, em_b2, em_g, em_lb,
                                   tnm1, nm_b1, tnm2, nm_b2, nm_g, nm_lb, bar);

  k_decode<<<128, 256, 0, stream>>>(v, tdc1, dec_b1, dec_w2, dec_b2, dout);
}

// Round 7
// 511.211 us; speedup vs baseline: 3.6013x; 3.6013x over previous
//
#include <hip/hip_runtime.h>

#define NN 8192
#define NE 65536

typedef __attribute__((ext_vector_type(8))) __bf16 bf16x8;
typedef __attribute__((ext_vector_type(4))) float f32x4;

typedef __attribute__((address_space(1))) const void* as1_cvoid;
typedef __attribute__((address_space(3))) void* as3_void;

__device__ __forceinline__ float bf2f(unsigned short s) {
  union { unsigned u; float f; } z; z.u = ((unsigned)s) << 16; return z.f;
}
__device__ __forceinline__ unsigned short f2bf(float f) {
  union { float f; unsigned u; } z; z.f = f;
  return (unsigned short)((z.u + 0x7FFFu + ((z.u >> 16) & 1u)) >> 16);
}
__device__ __forceinline__ void gl_lds16(const void* g, void* l) {
  __builtin_amdgcn_global_load_lds((as1_cvoid)g, (as3_void)l, 16, 0, 0);
}

__global__ __launch_bounds__(256) void k_zero_i32(int* p, int n) {
  int t = blockIdx.x * 256 + threadIdx.x;
  if (t < n) p[t] = 0;
}

// pack W (K x 128 row-major fp32) -> bf16 slabs of 4096 elems, slab layout
// [l4][n][8]: element (n, k=s*32+l4*8+j) at t = s*4096 + l4*1024 + n*8 + j.
__device__ __forceinline__ void packone(int t, const float* src, unsigned short* dst, int K) {
  int s = t >> 12;
  int rem = t & 4095;
  int l4 = rem >> 10;
  int rem2 = rem & 1023;
  int n = rem2 >> 3, j = rem2 & 7;
  int k = s * 32 + l4 * 8 + j;
  dst[t] = (k < K) ? f2bf(src[k * 128 + n]) : (unsigned short)0;
}

__global__ __launch_bounds__(256) void k_pack_all(
    const float* ve1, unsigned short* tve1, const float* ve2, unsigned short* tve2,
    const float* ee1, unsigned short* tee1, const float* ee2, unsigned short* tee2,
    const float* em1, unsigned short* tem1, const float* em2, unsigned short* tem2,
    const float* nm1, unsigned short* tnm1, const float* nm2, unsigned short* tnm2,
    const float* dc1, unsigned short* tdc1) {
  int t = blockIdx.x * 256 + threadIdx.x;
  if (t < 4096) packone(t, ve1, tve1, 8);
  else if (t < 20480) packone(t - 4096, ve2, tve2, 128);
  else if (t < 24576) packone(t - 20480, ee1, tee1, 6);
  else if (t < 40960) packone(t - 24576, ee2, tee2, 128);
  else if (t < 90112) packone(t - 40960, em1, tem1, 384);
  else if (t < 106496) packone(t - 90112, em2, tem2, 128);
  else if (t < 139264) packone(t - 106496, nm1, tnm1, 256);
  else if (t < 155648) packone(t - 139264, nm2, tnm2, 128);
  else if (t < 172032) packone(t - 155648, dc1, tdc1, 128);
}

__global__ __launch_bounds__(256) void k_prep_nodes(const int* __restrict__ sn,
                                                    const float* __restrict__ vf,
                                                    unsigned short* __restrict__ X) {
  int n = blockIdx.x * 256 + threadIdx.x;
  if (n >= NN) return;
  unsigned short* row = &X[(size_t)n * 32];
  int s = sn[n];
  row[0] = f2bf(s == 0 ? 1.f : 0.f);
  row[1] = f2bf(s == 1 ? 1.f : 0.f);
#pragma unroll
  for (int j = 0; j < 6; j++) row[2 + j] = f2bf(vf[n * 6 + j]);
#pragma unroll
  for (int j = 8; j < 32; j++) row[j] = 0;
}

__global__ __launch_bounds__(256) void k_count(const int* __restrict__ eidx,
                                               int* __restrict__ cnt) {
  int t = blockIdx.x * 256 + threadIdx.x;
  if (t >= NE) return;
  atomicAdd(&cnt[eidx[t]], 1);
}

__global__ __launch_bounds__(1024) void k_scan(const int* __restrict__ cnt,
                                               int* __restrict__ offs,
                                               int* __restrict__ cursor) {
  __shared__ int sd[1024];
  int tid = threadIdx.x;
  int loc[8];
  int s = 0;
#pragma unroll
  for (int i = 0; i < 8; i++) { loc[i] = s; s += cnt[tid * 8 + i]; }
  sd[tid] = s;
  __syncthreads();
  for (int o = 1; o < 1024; o <<= 1) {
    int vv = 0;
    if (tid >= o) vv = sd[tid - o];
    __syncthreads();
    sd[tid] += vv;
    __syncthreads();
  }
  int base = (tid == 0) ? 0 : sd[tid - 1];
#pragma unroll
  for (int i = 0; i < 8; i++) {
    int o = base + loc[i];
    offs[tid * 8 + i] = o;
    cursor[tid * 8 + i] = o;
  }
  if (tid == 1023) offs[8192] = sd[1023];
}

__global__ __launch_bounds__(256) void k_fill(const int* __restrict__ eidx,
                                              int* __restrict__ cursor,
                                              int* __restrict__ perm) {
  int t = blockIdx.x * 256 + threadIdx.x;
  if (t >= NE) return;
  int r = eidx[t];
  int pos = atomicAdd(&cursor[r], 1);
  perm[t] = pos;
}

// edge features written at PERMUTED slot (CSR order by destination node)
__global__ __launch_bounds__(256) void k_prep_edges(const int* __restrict__ eidx,
                                                    const float* __restrict__ wc,
                                                    const float* __restrict__ mc,
                                                    const int* __restrict__ perm,
                                                    unsigned short* __restrict__ X,
                                                    int* __restrict__ rowp,
                                                    int* __restrict__ colp) {
  int t = blockIdx.x * 256 + threadIdx.x;
  if (t >= NE) return;
  int r = eidx[t], c = eidx[NE + t];
  int p = perm[t];
  float ex = wc[c * 2] - wc[r * 2];
  float ey = wc[c * 2 + 1] - wc[r * 2 + 1];
  float mx = mc[c * 2] - mc[r * 2];
  float my = mc[c * 2 + 1] - mc[r * 2 + 1];
  unsigned short* row = &X[(size_t)p * 32];
  row[0] = f2bf(ex); row[1] = f2bf(ey); row[2] = f2bf(sqrtf(ex * ex + ey * ey));
  row[3] = f2bf(mx); row[4] = f2bf(my); row[5] = f2bf(sqrtf(mx * mx + my * my));
#pragma unroll
  for (int j = 6; j < 32; j++) row[j] = 0;
  rowp[p] = r;
  colp[p] = c;
}

// ---- edge step: 256 blocks x 512 threads (8 waves), 256 rows/block ----------
// ALL weights resident in LDS (128KB) staged once via global_load_lds; ONE
// barrier, then barrier-free. Wave owns 32 rows (2x16), B-frags shared.
__global__ __launch_bounds__(512, 1) void k_edge(
    const unsigned short* __restrict__ vbuf,
    unsigned short* __restrict__ ebuf,
    const int* __restrict__ rowp, const int* __restrict__ colp,
    const unsigned short* __restrict__ W1T, const float* __restrict__ b1,
    const unsigned short* __restrict__ W2T, const float* __restrict__ b2,
    const float* __restrict__ lng, const float* __restrict__ lnb) {
  __shared__ __align__(16) unsigned short Wres[65536];  // 128 KB
  __shared__ __align__(16) unsigned short H1c[16384];   // 32 KB
  const int tid = threadIdx.x;
  const int lane = tid & 63, wid = tid >> 6;
  const int l4 = lane >> 4, l15 = lane & 15;
  const int row0 = blockIdx.x * 256;
  const int hb = wid * 2048;

#pragma unroll
  for (int u = 0; u < 12; ++u)
    gl_lds16(W1T + (u * 512 + tid) * 8, &Wres[(u * 512 + tid) * 8]);
#pragma unroll
  for (int u = 0; u < 4; ++u)
    gl_lds16(W2T + (u * 512 + tid) * 8, &Wres[49152 + (u * 512 + tid) * 8]);

  int rg[2], ridx[2], cidx[2];
  bf16x8 af[2][12];
#pragma unroll
  for (int g = 0; g < 2; g++) {
    rg[g] = row0 + wid * 32 + g * 16 + l15;
    ridx[g] = rowp[rg[g]];
    cidx[g] = colp[rg[g]];
#pragma unroll
    for (int s = 0; s < 4; s++)
      af[g][s] = *(const bf16x8*)&vbuf[(size_t)ridx[g] * 128 + s * 32 + l4 * 8];
#pragma unroll
    for (int s = 0; s < 4; s++)
      af[g][4 + s] = *(const bf16x8*)&vbuf[(size_t)cidx[g] * 128 + s * 32 + l4 * 8];
#pragma unroll
    for (int s = 0; s < 4; s++)
      af[g][8 + s] = *(const bf16x8*)&ebuf[(size_t)rg[g] * 128 + s * 32 + l4 * 8];
  }
  __syncthreads();  // weights staged; barrier-free afterwards

  f32x4 acc1[2][8] = {};
#pragma unroll
  for (int s = 0; s < 12; ++s)
#pragma unroll
    for (int ct = 0; ct < 8; ct++) {
      bf16x8 b = *(const bf16x8*)&Wres[s * 4096 + l4 * 1024 + (ct * 16 + l15) * 8];
      acc1[0][ct] = __builtin_amdgcn_mfma_f32_16x16x32_bf16(af[0][s], b, acc1[0][ct], 0, 0, 0);
      acc1[1][ct] = __builtin_amdgcn_mfma_f32_16x16x32_bf16(af[1][s], b, acc1[1][ct], 0, 0, 0);
    }

  bf16x8 hf[2][4];
#pragma unroll
  for (int g = 0; g < 2; g++) {
#pragma unroll
    for (int ct = 0; ct < 8; ct++) {
      float bb = b1[ct * 16 + l15];
      int ch = ct * 2 + (l15 >> 3);
#pragma unroll
      for (int r = 0; r < 4; r++) {
        float h = fmaxf(acc1[g][ct][r] + bb, 0.f);
        H1c[hb + (ch * 16 + l4 * 4 + r) * 8 + (l15 & 7)] = f2bf(h);
      }
    }
#pragma unroll
    for (int kt = 0; kt < 4; kt++)
      hf[g][kt] = *(const bf16x8*)&H1c[hb + ((kt * 4 + l4) * 16 + l15) * 8];
  }

  f32x4 acc2[2][8] = {};
#pragma unroll
  for (int s = 0; s < 4; ++s)
#pragma unroll
    for (int ct = 0; ct < 8; ct++) {
      bf16x8 b = *(const bf16x8*)&Wres[49152 + s * 4096 + l4 * 1024 + (ct * 16 + l15) * 8];
      acc2[0][ct] = __builtin_amdgcn_mfma_f32_16x16x32_bf16(hf[0][s], b, acc2[0][ct], 0, 0, 0);
      acc2[1][ct] = __builtin_amdgcn_mfma_f32_16x16x32_bf16(hf[1][s], b, acc2[1][ct], 0, 0, 0);
    }

#pragma unroll
  for (int g = 0; g < 2; g++) {
    float s0[4] = {0, 0, 0, 0}, s1v[4] = {0, 0, 0, 0};
#pragma unroll
    for (int ct = 0; ct < 8; ct++) {
      float bb = b2[ct * 16 + l15];
#pragma unroll
      for (int r = 0; r < 4; r++) {
        int rr = row0 + wid * 32 + g * 16 + l4 * 4 + r;
        float x = acc2[g][ct][r] + bb + bf2f(ebuf[(size_t)rr * 128 + ct * 16 + l15]);
        acc2[g][ct][r] = x;
        s0[r] += x;
        s1v[r] += x * x;
      }
    }
#pragma unroll
    for (int m = 1; m < 16; m <<= 1)
#pragma unroll
      for (int r = 0; r < 4; r++) {
        s0[r] += __shfl_xor(s0[r], m, 64);
        s1v[r] += __shfl_xor(s1v[r], m, 64);
      }
#pragma unroll
    for (int ct = 0; ct < 8; ct++) {
      float gsc = lng[ct * 16 + l15], bsc = lnb[ct * 16 + l15];
      int ch = ct * 2 + (l15 >> 3);
#pragma unroll
      for (int r = 0; r < 4; r++) {
        float mean = s0[r] * (1.f / 128.f);
        float var = s1v[r] * (1.f / 128.f) - mean * mean;
        float y = (acc2[g][ct][r] - mean) * rsqrtf(var + 1e-5f) * gsc + bsc;
        H1c[hb + (ch * 16 + l4 * 4 + r) * 8 + (l15 & 7)] = f2bf(y);
      }
    }
#pragma unroll
    for (int i = 0; i < 4; i++) {
      *(uint4*)&ebuf[(size_t)(row0 + wid * 32 + g * 16 + l15) * 128 + (i * 4 + l4) * 8] =
          *(const uint4*)&H1c[hb + ((i * 4 + l4) * 16 + l15) * 8];
    }
  }
}

// ---- node step (fused agg): 256 blocks x 512 threads, 32 nodes/block --------
// Phase 1 (all 8 waves): contiguous segmented-sum of e (CSR order) -> LDS.
// Phase 2 (waves 0-1): MLP on [v|agg], K=256, weights LDS-resident.
__global__ __launch_bounds__(512, 1) void k_node(
    unsigned short* __restrict__ vbuf,
    const unsigned short* __restrict__ ebuf,
    const int* __restrict__ offs,
    const unsigned short* __restrict__ W1T, const float* __restrict__ b1,
    const unsigned short* __restrict__ W2T, const float* __restrict__ b2,
    const float* __restrict__ lng, const float* __restrict__ lnb) {
  __shared__ __align__(16) unsigned short Wres[49152];     // 96 KB
  __shared__ __align__(16) unsigned short Agg[32 * 136];   // pad-136 rows
  __shared__ __align__(16) unsigned short Hs[2][2048];     // per-MLP-wave scratch
  const int tid = threadIdx.x;
  const int lane = tid & 63, wid = tid >> 6;
  const int l4 = lane >> 4, l15 = lane & 15;
  const int nb0 = blockIdx.x * 32;

#pragma unroll
  for (int u = 0; u < 8; ++u)
    gl_lds16(W1T + (u * 512 + tid) * 8, &Wres[(u * 512 + tid) * 8]);
#pragma unroll
  for (int u = 0; u < 4; ++u)
    gl_lds16(W2T + (u * 512 + tid) * 8, &Wres[32768 + (u * 512 + tid) * 8]);

  {
    int node = tid >> 4, c = tid & 15;
    int n = nb0 + node;
    int beg = offs[n], end = offs[n + 1];
    float a0[8] = {0, 0, 0, 0, 0, 0, 0, 0}, a1[8] = {0, 0, 0, 0, 0, 0, 0, 0};
    int q = beg;
    for (; q + 2 <= end; q += 2) {
      uint4 u0 = *(const uint4*)&ebuf[(size_t)q * 128 + c * 8];
      uint4 u1 = *(const uint4*)&ebuf[(size_t)(q + 1) * 128 + c * 8];
      const unsigned short* p0 = (const unsigned short*)&u0;
      const unsigned short* p1 = (const unsigned short*)&u1;
#pragma unroll
      for (int j = 0; j < 8; j++) { a0[j] += bf2f(p0[j]); a1[j] += bf2f(p1[j]); }
    }
    if (q < end) {
      uint4 u0 = *(const uint4*)&ebuf[(size_t)q * 128 + c * 8];
      const unsigned short* p0 = (const unsigned short*)&u0;
#pragma unroll
      for (int j = 0; j < 8; j++) a0[j] += bf2f(p0[j]);
    }
    union { uint4 u; unsigned short s[8]; } t;
#pragma unroll
    for (int j = 0; j < 8; j++) t.s[j] = f2bf(a0[j] + a1[j]);
    *(uint4*)&Agg[node * 136 + c * 8] = t.u;
  }
  __syncthreads();

  if (wid < 2) {
    const int nrow = nb0 + wid * 16 + l15;
    bf16x8 av[8];
#pragma unroll
    for (int s = 0; s < 4; s++)
      av[s] = *(const bf16x8*)&vbuf[(size_t)nrow * 128 + s * 32 + l4 * 8];
#pragma unroll
    for (int s = 0; s < 4; s++)
      av[4 + s] = *(const bf16x8*)&Agg[(wid * 16 + l15) * 136 + s * 32 + l4 * 8];

    f32x4 acc1[8] = {};
#pragma unroll
    for (int sl = 0; sl < 8; ++sl)
#pragma unroll
      for (int ct = 0; ct < 8; ct++) {
        bf16x8 b = *(const bf16x8*)&Wres[sl * 4096 + l4 * 1024 + (ct * 16 + l15) * 8];
        acc1[ct] = __builtin_amdgcn_mfma_f32_16x16x32_bf16(av[sl], b, acc1[ct], 0, 0, 0);
      }

    unsigned short* hsb = &Hs[wid][0];
    bf16x8 hf[4];
#pragma unroll
    for (int ct = 0; ct < 8; ct++) {
      float bb = b1[ct * 16 + l15];
      int ch = ct * 2 + (l15 >> 3);
#pragma unroll
      for (int r = 0; r < 4; r++) {
        float h = fmaxf(acc1[ct][r] + bb, 0.f);
        hsb[(ch * 16 + l4 * 4 + r) * 8 + (l15 & 7)] = f2bf(h);
      }
    }
#pragma unroll
    for (int kt = 0; kt < 4; kt++)
      hf[kt] = *(const bf16x8*)&hsb[((kt * 4 + l4) * 16 + l15) * 8];

    f32x4 acc2[8] = {};
#pragma unroll
    for (int sl = 0; sl < 4; ++sl)
#pragma unroll
      for (int ct = 0; ct < 8; ct++) {
        bf16x8 b = *(const bf16x8*)&Wres[32768 + sl * 4096 + l4 * 1024 + (ct * 16 + l15) * 8];
        acc2[ct] = __builtin_amdgcn_mfma_f32_16x16x32_bf16(hf[sl], b, acc2[ct], 0, 0, 0);
      }

    float s0[4] = {0, 0, 0, 0}, s1v[4] = {0, 0, 0, 0};
#pragma unroll
    for (int ct = 0; ct < 8; ct++) {
      float bb = b2[ct * 16 + l15];
#pragma unroll
      for (int r = 0; r < 4; r++) {
        int rr = nb0 + wid * 16 + l4 * 4 + r;
        float x = acc2[ct][r] + bb + bf2f(vbuf[(size_t)rr * 128 + ct * 16 + l15]);
        acc2[ct][r] = x;
        s0[r] += x;
        s1v[r] += x * x;
      }
    }
#pragma unroll
    for (int m = 1; m < 16; m <<= 1)
#pragma unroll
      for (int r = 0; r < 4; r++) {
        s0[r] += __shfl_xor(s0[r], m, 64);
        s1v[r] += __shfl_xor(s1v[r], m, 64);
      }
#pragma unroll
    for (int ct = 0; ct < 8; ct++) {
      float gsc = lng[ct * 16 + l15], bsc = lnb[ct * 16 + l15];
      int ch = ct * 2 + (l15 >> 3);
#pragma unroll
      for (int r = 0; r < 4; r++) {
        float mean = s0[r] * (1.f / 128.f);
        float var = s1v[r] * (1.f / 128.f) - mean * mean;
        float y = (acc2[ct][r] - mean) * rsqrtf(var + 1e-5f) * gsc + bsc;
        hsb[(ch * 16 + l4 * 4 + r) * 8 + (l15 & 7)] = f2bf(y);
      }
    }
#pragma unroll
    for (int i = 0; i < 4; i++) {
      *(uint4*)&vbuf[(size_t)nrow * 128 + (i * 4 + l4) * 8] =
          *(const uint4*)&hsb[((i * 4 + l4) * 16 + l15) * 8];
    }
  }
}

// ------------------ encoder MLP (K=32 padded input, no residual) -------------
__global__ __launch_bounds__(256) void k_enc(const unsigned short* __restrict__ Xbuf,
                                             const unsigned short* __restrict__ W1T,
                                             const float* __restrict__ b1,
                                             const unsigned short* __restrict__ W2T,
                                             const float* __restrict__ b2,
                                             const float* __restrict__ lng,
                                             const float* __restrict__ lnb,
                                             unsigned short* __restrict__ outbuf) {
  __shared__ __align__(16) unsigned short Xt[64 * 40];
  __shared__ __align__(16) unsigned short H1[64 * 136];
  const int tid = threadIdx.x;
  const int row0 = blockIdx.x * 64;
  {
    int r = tid >> 2, c = tid & 3;
    *(uint4*)&Xt[r * 40 + c * 8] = *(const uint4*)&Xbuf[(size_t)(row0 + r) * 32 + c * 8];
  }
  __syncthreads();
  const int lane = tid & 63, wid = tid >> 6;
  const int l4 = lane >> 4, l15 = lane & 15;

  f32x4 acc1[8] = {};
  bf16x8 a = *(const bf16x8*)&Xt[(wid * 16 + l15) * 40 + l4 * 8];
#pragma unroll
  for (int ct = 0; ct < 8; ct++) {
    bf16x8 b = *(const bf16x8*)&W1T[l4 * 1024 + (ct * 16 + l15) * 8];
    acc1[ct] = __builtin_amdgcn_mfma_f32_16x16x32_bf16(a, b, acc1[ct], 0, 0, 0);
  }
#pragma unroll
  for (int ct = 0; ct < 8; ct++) {
    float bb = b1[ct * 16 + l15];
#pragma unroll
    for (int r = 0; r < 4; r++) {
      float h = fmaxf(acc1[ct][r] + bb, 0.f);
      H1[(wid * 16 + l4 * 4 + r) * 136 + ct * 16 + l15] = f2bf(h);
    }
  }
  bf16x8 hf[4];
#pragma unroll
  for (int kt = 0; kt < 4; kt++)
    hf[kt] = *(const bf16x8*)&H1[(wid * 16 + l15) * 136 + kt * 32 + l4 * 8];
  f32x4 acc2[8] = {};
#pragma unroll
  for (int kt = 0; kt < 4; kt++) {
#pragma unroll
    for (int ct = 0; ct < 8; ct++) {
      bf16x8 b = *(const bf16x8*)&W2T[kt * 4096 + l4 * 1024 + (ct * 16 + l15) * 8];
      acc2[ct] = __builtin_amdgcn_mfma_f32_16x16x32_bf16(hf[kt], b, acc2[ct], 0, 0, 0);
    }
  }
  float vals[8][4];
  float s0[4] = {0, 0, 0, 0}, s1[4] = {0, 0, 0, 0};
#pragma unroll
  for (int ct = 0; ct < 8; ct++) {
    float bb = b2[ct * 16 + l15];
#pragma unroll
    for (int r = 0; r < 4; r++) {
      float x = acc2[ct][r] + bb;
      vals[ct][r] = x;
      s0[r] += x;
      s1[r] += x * x;
    }
  }
#pragma unroll
  for (int m = 1; m < 16; m <<= 1) {
#pragma unroll
    for (int r = 0; r < 4; r++) {
      s0[r] += __shfl_xor(s0[r], m, 64);
      s1[r] += __shfl_xor(s1[r], m, 64);
    }
  }
#pragma unroll
  for (int ct = 0; ct < 8; ct++) {
    int colc = ct * 16 + l15;
    float g = lng[colc], bb = lnb[colc];
#pragma unroll
    for (int r = 0; r < 4; r++) {
      float mean = s0[r] * (1.f / 128.f);
      float var = s1[r] * (1.f / 128.f) - mean * mean;
      float y = (vals[ct][r] - mean) * rsqrtf(var + 1e-5f) * g + bb;
      H1[(wid * 16 + l4 * 4 + r) * 136 + colc] = f2bf(y);
    }
  }
#pragma unroll
  for (int i = 0; i < 4; i++) {
    int j = lane + i * 64;
    int r = j >> 4, ch = j & 15;
    *(uint4*)&outbuf[(size_t)(row0 + wid * 16 + r) * 128 + ch * 8] =
        *(const uint4*)&H1[(wid * 16 + r) * 136 + ch * 8];
  }
}

__global__ __launch_bounds__(256) void k_decode(const unsigned short* __restrict__ vbuf,
                                                const unsigned short* __restrict__ W1T,
                                                const float* __restrict__ b1,
                                                const float* __restrict__ w2,
                                                const float* __restrict__ b2,
                                                float* __restrict__ out) {
  __shared__ __align__(16) unsigned short Xt[64 * 136];
  __shared__ __align__(16) unsigned short H1[64 * 136];
  const int tid = threadIdx.x;
  const int row0 = blockIdx.x * 64;
  for (int i = tid; i < 64 * 16; i += 256) {
    int r = i >> 4, c = i & 15;
    *(uint4*)&Xt[r * 136 + c * 8] = *(const uint4*)&vbuf[(size_t)(row0 + r) * 128 + c * 8];
  }
  __syncthreads();
  const int lane = tid & 63, wid = tid >> 6;
  const int l4 = lane >> 4, l15 = lane & 15;
  f32x4 acc1[8] = {};
#pragma unroll
  for (int kt = 0; kt < 4; kt++) {
    bf16x8 a = *(const bf16x8*)&Xt[(wid * 16 + l15) * 136 + kt * 32 + l4 * 8];
#pragma unroll
    for (int ct = 0; ct < 8; ct++) {
      bf16x8 b = *(const bf16x8*)&W1T[kt * 4096 + l4 * 1024 + (ct * 16 + l15) * 8];
      acc1[ct] = __builtin_amdgcn_mfma_f32_16x16x32_bf16(a, b, acc1[ct], 0, 0, 0);
    }
  }
#pragma unroll
  for (int ct = 0; ct < 8; ct++) {
    float bb = b1[ct * 16 + l15];
#pragma unroll
    for (int r = 0; r < 4; r++) {
      float h = fmaxf(acc1[ct][r] + bb, 0.f);
      H1[(wid * 16 + l4 * 4 + r) * 136 + ct * 16 + l15] = f2bf(h);
    }
  }
  __syncthreads();
  for (int i = tid; i < 64 * 6; i += 256) {
    int r = i / 6, o = i % 6;
    float s = b2[o];
    for (int k = 0; k < 128; k++) s += bf2f(H1[r * 136 + k]) * w2[k * 6 + o];
    out[(size_t)(row0 + r) * 6 + o] = s;
  }
}

extern "C" void kernel_launch(void* const* d_in, const int* in_sizes, int n_in,
                              void* d_out, int out_size, void* d_ws, size_t ws_size,
                              hipStream_t stream) {
  (void)in_sizes; (void)n_in; (void)out_size; (void)ws_size;
  const float* wc = (const float*)d_in[0];
  const float* vf = (const float*)d_in[1];
  const float* mc = (const float*)d_in[2];
  const float* ve_w1 = (const float*)d_in[3];
  const float* ve_b1 = (const float*)d_in[4];
  const float* ve_w2 = (const float*)d_in[5];
  const float* ve_b2 = (const float*)d_in[6];
  const float* ee_w1 = (const float*)d_in[7];
  const float* ee_b1 = (const float*)d_in[8];
  const float* ee_w2 = (const float*)d_in[9];
  const float* ee_b2 = (const float*)d_in[10];
  const float* enc_g = (const float*)d_in[11];
  const float* enc_b = (const float*)d_in[12];
  const float* em_w1 = (const float*)d_in[13];
  const float* em_b1 = (const float*)d_in[14];
  const float* em_w2 = (const float*)d_in[15];
  const float* em_b2 = (const float*)d_in[16];
  const float* em_g = (const float*)d_in[17];
  const float* em_lb = (const float*)d_in[18];
  const float* nm_w1 = (const float*)d_in[19];
  const float* nm_b1 = (const float*)d_in[20];
  const float* nm_w2 = (const float*)d_in[21];
  const float* nm_b2 = (const float*)d_in[22];
  const float* nm_g = (const float*)d_in[23];
  const float* nm_lb = (const float*)d_in[24];
  const float* dec_w1 = (const float*)d_in[25];
  const float* dec_b1 = (const float*)d_in[26];
  const float* dec_w2 = (const float*)d_in[27];
  const float* dec_b2 = (const float*)d_in[28];
  const int* eidx = (const int*)d_in[29];
  const int* sn = (const int*)d_in[30];
  float* dout = (float*)d_out;

  char* w = (char*)d_ws;
  size_t off = 0;
  auto alloc = [&](size_t bytes) {
    char* p = w + off;
    off += (bytes + 255) & ~(size_t)255;
    return p;
  };
  unsigned short* v = (unsigned short*)alloc((size_t)NN * 128 * 2);
  unsigned short* e = (unsigned short*)alloc((size_t)NE * 128 * 2);
  unsigned short* Xve = (unsigned short*)alloc((size_t)NN * 32 * 2);
  unsigned short* Xee = (unsigned short*)alloc((size_t)NE * 32 * 2);
  unsigned short* tve1 = (unsigned short*)alloc(128 * 32 * 2);
  unsigned short* tve2 = (unsigned short*)alloc(128 * 128 * 2);
  unsigned short* tee1 = (unsigned short*)alloc(128 * 32 * 2);
  unsigned short* tee2 = (unsigned short*)alloc(128 * 128 * 2);
  unsigned short* tem1 = (unsigned short*)alloc(128 * 384 * 2);
  unsigned short* tem2 = (unsigned short*)alloc(128 * 128 * 2);
  unsigned short* tnm1 = (unsigned short*)alloc(128 * 256 * 2);
  unsigned short* tnm2 = (unsigned short*)alloc(128 * 128 * 2);
  unsigned short* tdc1 = (unsigned short*)alloc(128 * 128 * 2);
  int* cnt = (int*)alloc(NN * 4);
  int* offsb = (int*)alloc((NN + 1) * 4);
  int* cursor = (int*)alloc(NN * 4);
  int* perm = (int*)alloc((size_t)NE * 4);
  int* rowp = (int*)alloc((size_t)NE * 4);
  int* colp = (int*)alloc((size_t)NE * 4);

  k_zero_i32<<<32, 256, 0, stream>>>(cnt, NN);
  k_pack_all<<<672, 256, 0, stream>>>(ve_w1, tve1, ve_w2, tve2, ee_w1, tee1, ee_w2, tee2,
                                      em_w1, tem1, em_w2, tem2, nm_w1, tnm1, nm_w2, tnm2,
                                      dec_w1, tdc1);
  k_prep_nodes<<<32, 256, 0, stream>>>(sn, vf, Xve);
  k_count<<<256, 256, 0, stream>>>(eidx, cnt);
  k_scan<<<1, 1024, 0, stream>>>(cnt, offsb, cursor);
  k_fill<<<256, 256, 0, stream>>>(eidx, cursor, perm);
  k_prep_edges<<<256, 256, 0, stream>>>(eidx, wc, mc, perm, Xee, rowp, colp);

  k_enc<<<128, 256, 0, stream>>>(Xve, tve1, ve_b1, tve2, ve_b2, enc_g, enc_b, v);
  k_enc<<<1024, 256, 0, stream>>>(Xee, tee1, ee_b1, tee2, ee_b2, enc_g, enc_b, e);
  for (int s = 0; s < 15; ++s) {
    k_edge<<<256, 512, 0, stream>>>(v, e, rowp, colp, tem1, em_b1, tem2, em_b2, em_g, em_lb);
    k_node<<<256, 512, 0, stream>>>(v, e, offsb, tnm1, nm_b1, tnm2, nm_b2, nm_g, nm_lb);
  }
  k_decode<<<128, 256, 0, stream>>>(v, tdc1, dec_b1, dec_w2, dec_b2, dout);
}